// Round 8
// baseline (315.541 us; speedup 1.0000x reference)
//
#include <hip/hip_runtime.h>

// GCN 4-layer: 29->96->128->64->32, N=50000, E=800000 (+self loops).
// Round 8 = round 7 (collapsed layers 2-4: out = A^3(h1 W234) + c2 v2 + c1 v1
// + b4) plus: place_ell 4 edges/thread (4 atomic chains in flight), agg32
// unrolled to 8 gathers in flight, heavy fusion (9 launches, was 15):
//  - prep_all = dis + ell-pad + xpad + sentinels
//  - wcomb    = W34 (LDS) -> W234, v1, v2 in one block
//  - width-1 aggs (c1, c2) ride as extra blocks on agg32 dispatches
//  - both GEMMs fused: h1 stays in LDS (saves 38 MB HBM round-trip)
// NOTE: harness delivers integer inputs as int32.

constexpr int NN  = 50000;
constexpr int CAP = 64;    // max in-degree; Poisson(16) over 50K => P(>=64) ~ 0
constexpr int AGB = (NN * 8 + 255) / 256;   // blocks for width-32 agg
constexpr int C1B = (NN + 255) / 256;       // extra blocks for width-1 agg

// 4 edges/thread: int4 index loads, 4 independent atomic->store chains.
__global__ void place_ell_kernel(const int* __restrict__ row, const int* __restrict__ col,
                                 int* __restrict__ cnt, int* __restrict__ ell, int E) {
    const int t  = blockIdx.x * blockDim.x + threadIdx.x;
    const int e0 = t * 4;
    if (e0 + 4 <= E) {
        const int4 c4 = *(const int4*)(col + e0);
        const int4 r4 = *(const int4*)(row + e0);
        int p0 = -1, p1 = -1, p2 = -1, p3 = -1;
        if ((unsigned)c4.x < (unsigned)NN) p0 = atomicAdd(&cnt[c4.x], 1);
        if ((unsigned)c4.y < (unsigned)NN) p1 = atomicAdd(&cnt[c4.y], 1);
        if ((unsigned)c4.z < (unsigned)NN) p2 = atomicAdd(&cnt[c4.z], 1);
        if ((unsigned)c4.w < (unsigned)NN) p3 = atomicAdd(&cnt[c4.w], 1);
        if ((unsigned)p0 < CAP) ell[c4.x * CAP + p0] = r4.x;
        if ((unsigned)p1 < CAP) ell[c4.y * CAP + p1] = r4.y;
        if ((unsigned)p2 < CAP) ell[c4.z * CAP + p2] = r4.z;
        if ((unsigned)p3 < CAP) ell[c4.w * CAP + p3] = r4.w;
    } else {
        for (int e = e0; e < E; ++e) {
            int c = col[e], r = row[e];
            if ((unsigned)c < (unsigned)NN && (unsigned)r < (unsigned)NN) {
                int pos = atomicAdd(&cnt[c], 1);
                if (pos < CAP) ell[c * CAP + pos] = r;
            }
        }
    }
}

// Fused: dis, ELL sentinel-padding, x -> 32-wide pre-scaled pad, zero rows.
__global__ void prep_all_kernel(const int* __restrict__ cnt, int* __restrict__ ell,
                                const float* __restrict__ x, float* __restrict__ dis,
                                float* __restrict__ Ba, float* __restrict__ Bb,
                                float* __restrict__ c1d) {
    const int idx = blockIdx.x * blockDim.x + threadIdx.x;
    if (idx < NN * 32) {
        const int n = idx >> 5, f = idx & 31;
        int m = cnt[n]; if (m > CAP) m = CAP;
        const float d = rsqrtf((float)m + 1.0f);     // +1 = self loop
        Ba[idx] = (f < 29) ? x[n * 29 + f] * d : 0.f;
        if (f == 31) dis[n] = d;
        if (f == 30) {                               // pad list to multiple of 4
            int mp = (m + 3) & ~3; if (mp > CAP) mp = CAP;
            for (int k = m; k < mp; ++k) ell[n * CAP + k] = NN;
        }
    } else {
        const int i = idx - NN * 32;
        if (i < 32) { Ba[NN * 32 + i] = 0.f; Bb[NN * 32 + i] = 0.f; }
        else if (i == 32) dis[NN] = 0.f;
        else if (i == 33) c1d[NN] = 0.f;
    }
}

// One block: W34 = W3@W4 (into LDS), v1 = b3@W4; then W234 = W2@W34, v2 = b2@W34.
__global__ void wcomb_kernel(const float* __restrict__ W2, const float* __restrict__ W3,
                             const float* __restrict__ W4, const float* __restrict__ b2,
                             const float* __restrict__ b3, float* __restrict__ W234,
                             float* __restrict__ v1, float* __restrict__ v2) {
    __shared__ float w34[128 * 32];
    const int t = threadIdx.x;
    for (int i = t; i < 128 * 32; i += 1024) {
        const int r = i >> 5, j = i & 31;
        float a = 0.f;
        for (int k = 0; k < 64; ++k) a = fmaf(W3[r * 64 + k], W4[k * 32 + j], a);
        w34[i] = a;
    }
    if (t < 32) {
        float a = 0.f;
        for (int k = 0; k < 64; ++k) a = fmaf(b3[k], W4[k * 32 + t], a);
        v1[t] = a;
    }
    __syncthreads();
    for (int i = t; i < 96 * 32; i += 1024) {
        const int r = i >> 5, j = i & 31;
        float a = 0.f;
        for (int k = 0; k < 128; ++k) a = fmaf(W2[r * 128 + k], w34[k * 32 + j], a);
        W234[i] = a;
    }
    if (t < 32) {
        float a = 0.f;
        for (int k = 0; k < 128; ++k) a = fmaf(b2[k], w34[k * 32 + t], a);
        v2[t] = a;
    }
}

// Width-32 pull aggregation, 8 gathers in flight; extra blocks (>= AGB) do a
// width-1 aggregation (c1 / c2 computation) when w1in != nullptr.
// MODE: 0 plain out=dis*acc ; 1 chain out=dis^2*acc ; 2 final +rank-1 fixups.
template<int MODE>
__global__ void agg32_kernel(const float* __restrict__ hs, const int* __restrict__ cnt,
                             const int* __restrict__ ell, const float* __restrict__ dis,
                             const float* __restrict__ c1, const float* __restrict__ c2,
                             const float* __restrict__ v1, const float* __restrict__ v2,
                             const float* __restrict__ b4, float* __restrict__ out,
                             const float* __restrict__ w1in, float* __restrict__ w1out,
                             float* __restrict__ w1outd) {
    if (blockIdx.x >= AGB) {                    // folded width-1 aggregation
        const int n = (blockIdx.x - AGB) * 256 + threadIdx.x;
        if (n >= NN) return;
        float acc = w1in[n];
        int m = cnt[n]; if (m > CAP) m = CAP;
        const int m4 = (m + 3) >> 2;
        const int4* ip = (const int4*)(ell + n * CAP);
        for (int t = 0; t < m4; ++t) {
            const int4 s = ip[t];
            acc += (w1in[s.x] + w1in[s.y]) + (w1in[s.z] + w1in[s.w]);
        }
        const float r = dis[n] * acc;
        w1out[n] = r;
        if (w1outd) w1outd[n] = r * dis[n];
        return;
    }
    const int idx = blockIdx.x * blockDim.x + threadIdx.x;
    if (idx >= NN * 8) return;
    const int n = idx >> 3, c = idx & 7;
    const float4* hpc = (const float4*)hs + c;
    float4 acc = hpc[n * 8];                    // self-loop term
    int m = cnt[n]; if (m > CAP) m = CAP;
    const int m4 = (m + 3) >> 2;
    const int4* ip = (const int4*)(ell + n * CAP);
    int t = 0;
    for (; t + 2 <= m4; t += 2) {               // 8 independent gathers in flight
        const int4 s0 = ip[t], s1 = ip[t + 1];
        const float4 g0 = hpc[s0.x * 8], g1 = hpc[s0.y * 8];
        const float4 g2 = hpc[s0.z * 8], g3 = hpc[s0.w * 8];
        const float4 g4 = hpc[s1.x * 8], g5 = hpc[s1.y * 8];
        const float4 g6 = hpc[s1.z * 8], g7 = hpc[s1.w * 8];
        acc.x += ((g0.x + g1.x) + (g2.x + g3.x)) + ((g4.x + g5.x) + (g6.x + g7.x));
        acc.y += ((g0.y + g1.y) + (g2.y + g3.y)) + ((g4.y + g5.y) + (g6.y + g7.y));
        acc.z += ((g0.z + g1.z) + (g2.z + g3.z)) + ((g4.z + g5.z) + (g6.z + g7.z));
        acc.w += ((g0.w + g1.w) + (g2.w + g3.w)) + ((g4.w + g5.w) + (g6.w + g7.w));
    }
    if (t < m4) {
        const int4 s = ip[t];
        const float4 g0 = hpc[s.x * 8], g1 = hpc[s.y * 8];
        const float4 g2 = hpc[s.z * 8], g3 = hpc[s.w * 8];
        acc.x += (g0.x + g1.x) + (g2.x + g3.x);
        acc.y += (g0.y + g1.y) + (g2.y + g3.y);
        acc.z += (g0.z + g1.z) + (g2.z + g3.z);
        acc.w += (g0.w + g1.w) + (g2.w + g3.w);
    }
    const float d = dis[n];
    float4 r;
    if (MODE == 0) {
        r.x = acc.x * d; r.y = acc.y * d; r.z = acc.z * d; r.w = acc.w * d;
    } else if (MODE == 1) {
        const float d2 = d * d;
        r.x = acc.x * d2; r.y = acc.y * d2; r.z = acc.z * d2; r.w = acc.w * d2;
    } else {
        const float a1 = c1[n], a2 = c2[n];
        const float4 w1 = ((const float4*)v1)[c];
        const float4 w2 = ((const float4*)v2)[c];
        const float4 bb = ((const float4*)b4)[c];
        r.x = fmaf(acc.x, d, fmaf(a1, w1.x, fmaf(a2, w2.x, bb.x)));
        r.y = fmaf(acc.y, d, fmaf(a1, w1.y, fmaf(a2, w2.y, bb.y)));
        r.z = fmaf(acc.z, d, fmaf(a1, w1.z, fmaf(a2, w2.z, bb.z)));
        r.w = fmaf(acc.w, d, fmaf(a1, w1.w, fmaf(a2, w2.w, bb.w)));
    }
    ((float4*)out)[idx] = r;
}

// Fused dense path: h1d = relu(Xa@W1 + b1)*dis (kept in LDS), g = h1d@W234.
// 192 threads, 16 nodes per block. Phase A: round-6 register blocking
// (cg of 4 cols x node-pair). Phase B: 128 threads, 1 node x 4 cols each.
__global__ void gemm_fused_kernel(const float* __restrict__ X, const float* __restrict__ W1,
                                  const float* __restrict__ b1, const float* __restrict__ dis,
                                  const float* __restrict__ W234, float* __restrict__ G) {
    constexpr int NPB = 16, RSX = 36, RSH = 104;
    __shared__ float xs[NPB * RSX];
    __shared__ float hsm[NPB * RSH];
    const int tid = threadIdx.x;
    const int n0  = blockIdx.x * NPB;

    const float4* Xv = (const float4*)(X + (size_t)n0 * 32);
    for (int i = tid; i < NPB * 8; i += 192) {
        const int nl = i >> 3, r = i & 7;
        float4 v = make_float4(0.f, 0.f, 0.f, 0.f);
        if (n0 + nl < NN) v = Xv[nl * 8 + r];
        *(float4*)(xs + nl * RSX + r * 4) = v;
    }
    __syncthreads();

    {   // phase A: 29 -> 96, relu(+b1)*dis, result to LDS
        const int cg = tid % 24, g = tid / 24;
        const float* x0 = xs + (2 * g) * RSX;
        const float* x1 = x0 + RSX;
        const float4* Wv = (const float4*)W1;
        float4 a0 = make_float4(0.f, 0.f, 0.f, 0.f);
        float4 a1 = make_float4(0.f, 0.f, 0.f, 0.f);
#pragma unroll
        for (int k = 0; k < 29; ++k) {
            const float4 w = Wv[k * 24 + cg];
            const float v0 = x0[k], v1 = x1[k];
            a0.x = fmaf(v0, w.x, a0.x); a0.y = fmaf(v0, w.y, a0.y);
            a0.z = fmaf(v0, w.z, a0.z); a0.w = fmaf(v0, w.w, a0.w);
            a1.x = fmaf(v1, w.x, a1.x); a1.y = fmaf(v1, w.y, a1.y);
            a1.z = fmaf(v1, w.z, a1.z); a1.w = fmaf(v1, w.w, a1.w);
        }
        const float4 bb = ((const float4*)b1)[cg];
#pragma unroll
        for (int h = 0; h < 2; ++h) {
            const int nl = 2 * g + h, node = n0 + nl;
            const float d = (node < NN) ? dis[node] : 0.f;
            const float4 a = h ? a1 : a0;
            float4 r;
            r.x = fmaxf(a.x + bb.x, 0.f) * d; r.y = fmaxf(a.y + bb.y, 0.f) * d;
            r.z = fmaxf(a.z + bb.z, 0.f) * d; r.w = fmaxf(a.w + bb.w, 0.f) * d;
            *(float4*)(hsm + nl * RSH + cg * 4) = r;
        }
    }
    __syncthreads();

    if (tid < 128) {  // phase B: 96 -> 32 raw
        const int nl = tid >> 3, cg = tid & 7;
        const float* hr = hsm + nl * RSH;
        const float4* Wv = (const float4*)W234;
        float4 a = make_float4(0.f, 0.f, 0.f, 0.f);
#pragma unroll 8
        for (int k = 0; k < 96; ++k) {
            const float4 w = Wv[k * 8 + cg];
            const float v = hr[k];
            a.x = fmaf(v, w.x, a.x); a.y = fmaf(v, w.y, a.y);
            a.z = fmaf(v, w.z, a.z); a.w = fmaf(v, w.w, a.w);
        }
        const int node = n0 + nl;
        if (node < NN) ((float4*)(G + (size_t)node * 32))[cg] = a;
    }
}

extern "C" void kernel_launch(void* const* d_in, const int* in_sizes, int n_in,
                              void* d_out, int out_size, void* d_ws, size_t ws_size,
                              hipStream_t stream) {
    const float* x  = (const float*)d_in[0];
    const int*   ei = (const int*)d_in[1];           // int32 (harness converts)
    const float* W1 = (const float*)d_in[2]; const float* b1 = (const float*)d_in[3];
    const float* W2 = (const float*)d_in[4]; const float* b2 = (const float*)d_in[5];
    const float* W3 = (const float*)d_in[6]; const float* b3 = (const float*)d_in[7];
    const float* W4 = (const float*)d_in[8]; const float* b4 = (const float*)d_in[9];
    float* out = (float*)d_out;

    const int E = in_sizes[1] / 2;          // 800000
    const int* row = ei;
    const int* col = ei + E;

    // Workspace (4B elems, 16B-aligned sections), ~27 MB:
    int*   cnt  = (int*)d_ws;                       // 50048
    float* dis  = (float*)(cnt + 50048);            // 50056 (uses [NN])
    int*   ell  = (int*)(dis + 50056);              // NN*CAP
    float* c1   = (float*)(ell + (size_t)NN * CAP); // 50056
    float* c1d  = c1 + 50056;                       // 50056 (uses [NN])
    float* c2   = c1d + 50056;                      // 50056
    float* W234 = c2 + 50056;                       // 3072
    float* v1   = W234 + 3072;                      // 32
    float* v2   = v1 + 32;                          // 32
    float* Ba   = v2 + 32;                          // (NN+1)*32
    float* Bb   = Ba + 1600064;                     // (NN+1)*32

    // 1. zero counters
    hipMemsetAsync(cnt, 0, 50048 * sizeof(int), stream);
    // 2. build ELL (4 edges/thread)
    place_ell_kernel<<<(E / 4 + 255) / 256, 256, 0, stream>>>(row, col, cnt, ell, E);
    // 3. dis + pad + xpad + sentinels
    prep_all_kernel<<<(NN * 32 + 64 + 255) / 256, 256, 0, stream>>>(cnt, ell, x, dis, Ba, Bb, c1d);
    // 4. collapsed weights
    wcomb_kernel<<<1, 1024, 0, stream>>>(W2, W3, W4, b2, b3, W234, v1, v2);
    // 5. layer-1 pre-agg (Ba->Bb) + folded c1 = A.1
    agg32_kernel<0><<<AGB + C1B, 256, 0, stream>>>(Ba, cnt, ell, dis,
        nullptr, nullptr, nullptr, nullptr, nullptr, Bb, dis, c1, c1d);
    // 6. fused dense: h1 in LDS, g = h1d@W234 (Bb->Ba)
    gemm_fused_kernel<<<(NN + 15) / 16, 192, 0, stream>>>(Bb, W1, b1, dis, W234, Ba);
    // 7. hop 1 (Ba->Bb) + folded c2 = A.(c1*dis)
    agg32_kernel<1><<<AGB + C1B, 256, 0, stream>>>(Ba, cnt, ell, dis,
        nullptr, nullptr, nullptr, nullptr, nullptr, Bb, c1d, c2, nullptr);
    // 8. hop 2 (Bb->Ba)
    agg32_kernel<1><<<AGB, 256, 0, stream>>>(Bb, cnt, ell, dis,
        nullptr, nullptr, nullptr, nullptr, nullptr, Ba, nullptr, nullptr, nullptr);
    // 9. hop 3 + rank-1 bias fixups (Ba->out)
    agg32_kernel<2><<<AGB, 256, 0, stream>>>(Ba, cnt, ell, dis,
        c1, c2, v1, v2, b4, out, nullptr, nullptr, nullptr);
}

// Round 9
// 255.167 us; speedup vs baseline: 1.2366x; 1.2366x over previous
//
#include <hip/hip_runtime.h>

// GCN 4-layer: 29->96->128->64->32, N=50000, E=800000 (+self loops).
// Round 9 = round 8 minus the fused-GEMM mistake (it spilled: VGPR=64 cap,
// 274 MB scratch traffic, 95 us). Dense path back to two register-blocked
// GEMMs (round 6/7 proven, ~32 VGPR, no spill). Kept from round 8:
//  - collapsed layers 2-4: out = A^3(h1 W234) + c2 v2 + c1 v1 + b4
//  - place_ell 4 edges/thread (4 atomic chains in flight)
//  - agg32 with 8 gathers in flight (row-major ELL, int4 indices)
//  - prep_all / wcomb fusion; width-1 aggs folded into agg32 dispatches
// NOTE: harness delivers integer inputs as int32.

constexpr int NN  = 50000;
constexpr int CAP = 64;    // max in-degree; Poisson(16) over 50K => P(>=64) ~ 0
constexpr int AGB = (NN * 8 + 255) / 256;   // blocks for width-32 agg
constexpr int C1B = (NN + 255) / 256;       // extra blocks for width-1 agg

// 4 edges/thread: int4 index loads, 4 independent atomic->store chains.
__global__ void place_ell_kernel(const int* __restrict__ row, const int* __restrict__ col,
                                 int* __restrict__ cnt, int* __restrict__ ell, int E) {
    const int t  = blockIdx.x * blockDim.x + threadIdx.x;
    const int e0 = t * 4;
    if (e0 + 4 <= E) {
        const int4 c4 = *(const int4*)(col + e0);
        const int4 r4 = *(const int4*)(row + e0);
        int p0 = -1, p1 = -1, p2 = -1, p3 = -1;
        if ((unsigned)c4.x < (unsigned)NN) p0 = atomicAdd(&cnt[c4.x], 1);
        if ((unsigned)c4.y < (unsigned)NN) p1 = atomicAdd(&cnt[c4.y], 1);
        if ((unsigned)c4.z < (unsigned)NN) p2 = atomicAdd(&cnt[c4.z], 1);
        if ((unsigned)c4.w < (unsigned)NN) p3 = atomicAdd(&cnt[c4.w], 1);
        if ((unsigned)p0 < CAP) ell[c4.x * CAP + p0] = r4.x;
        if ((unsigned)p1 < CAP) ell[c4.y * CAP + p1] = r4.y;
        if ((unsigned)p2 < CAP) ell[c4.z * CAP + p2] = r4.z;
        if ((unsigned)p3 < CAP) ell[c4.w * CAP + p3] = r4.w;
    } else {
        for (int e = e0; e < E; ++e) {
            int c = col[e], r = row[e];
            if ((unsigned)c < (unsigned)NN && (unsigned)r < (unsigned)NN) {
                int pos = atomicAdd(&cnt[c], 1);
                if (pos < CAP) ell[c * CAP + pos] = r;
            }
        }
    }
}

// Fused: dis, ELL sentinel-padding, x -> 32-wide pre-scaled pad, zero rows.
__global__ void prep_all_kernel(const int* __restrict__ cnt, int* __restrict__ ell,
                                const float* __restrict__ x, float* __restrict__ dis,
                                float* __restrict__ Ba, float* __restrict__ Bb,
                                float* __restrict__ c1d) {
    const int idx = blockIdx.x * blockDim.x + threadIdx.x;
    if (idx < NN * 32) {
        const int n = idx >> 5, f = idx & 31;
        int m = cnt[n]; if (m > CAP) m = CAP;
        const float d = rsqrtf((float)m + 1.0f);     // +1 = self loop
        Ba[idx] = (f < 29) ? x[n * 29 + f] * d : 0.f;
        if (f == 31) dis[n] = d;
        if (f == 30) {                               // pad list to multiple of 4
            int mp = (m + 3) & ~3; if (mp > CAP) mp = CAP;
            for (int k = m; k < mp; ++k) ell[n * CAP + k] = NN;
        }
    } else {
        const int i = idx - NN * 32;
        if (i < 32) { Ba[NN * 32 + i] = 0.f; Bb[NN * 32 + i] = 0.f; }
        else if (i == 32) dis[NN] = 0.f;
        else if (i == 33) c1d[NN] = 0.f;
    }
}

// One block: W34 = W3@W4 (into LDS), v1 = b3@W4; then W234 = W2@W34, v2 = b2@W34.
__global__ void wcomb_kernel(const float* __restrict__ W2, const float* __restrict__ W3,
                             const float* __restrict__ W4, const float* __restrict__ b2,
                             const float* __restrict__ b3, float* __restrict__ W234,
                             float* __restrict__ v1, float* __restrict__ v2) {
    __shared__ float w34[128 * 32];
    const int t = threadIdx.x;
    for (int i = t; i < 128 * 32; i += 1024) {
        const int r = i >> 5, j = i & 31;
        float a = 0.f;
        for (int k = 0; k < 64; ++k) a = fmaf(W3[r * 64 + k], W4[k * 32 + j], a);
        w34[i] = a;
    }
    if (t < 32) {
        float a = 0.f;
        for (int k = 0; k < 64; ++k) a = fmaf(b3[k], W4[k * 32 + t], a);
        v1[t] = a;
    }
    __syncthreads();
    for (int i = t; i < 96 * 32; i += 1024) {
        const int r = i >> 5, j = i & 31;
        float a = 0.f;
        for (int k = 0; k < 128; ++k) a = fmaf(W2[r * 128 + k], w34[k * 32 + j], a);
        W234[i] = a;
    }
    if (t < 32) {
        float a = 0.f;
        for (int k = 0; k < 128; ++k) a = fmaf(b2[k], w34[k * 32 + t], a);
        v2[t] = a;
    }
}

// Width-32 pull aggregation, 8 gathers in flight; extra blocks (>= AGB) do a
// width-1 aggregation (c1 / c2 computation) when w1in != nullptr.
// MODE: 0 plain out=dis*acc ; 1 chain out=dis^2*acc ; 2 final +rank-1 fixups.
template<int MODE>
__global__ void agg32_kernel(const float* __restrict__ hs, const int* __restrict__ cnt,
                             const int* __restrict__ ell, const float* __restrict__ dis,
                             const float* __restrict__ c1, const float* __restrict__ c2,
                             const float* __restrict__ v1, const float* __restrict__ v2,
                             const float* __restrict__ b4, float* __restrict__ out,
                             const float* __restrict__ w1in, float* __restrict__ w1out,
                             float* __restrict__ w1outd) {
    if (blockIdx.x >= AGB) {                    // folded width-1 aggregation
        const int n = (blockIdx.x - AGB) * 256 + threadIdx.x;
        if (n >= NN) return;
        float acc = w1in[n];
        int m = cnt[n]; if (m > CAP) m = CAP;
        const int m4 = (m + 3) >> 2;
        const int4* ip = (const int4*)(ell + n * CAP);
        for (int t = 0; t < m4; ++t) {
            const int4 s = ip[t];
            acc += (w1in[s.x] + w1in[s.y]) + (w1in[s.z] + w1in[s.w]);
        }
        const float r = dis[n] * acc;
        w1out[n] = r;
        if (w1outd) w1outd[n] = r * dis[n];
        return;
    }
    const int idx = blockIdx.x * blockDim.x + threadIdx.x;
    if (idx >= NN * 8) return;
    const int n = idx >> 3, c = idx & 7;
    const float4* hpc = (const float4*)hs + c;
    float4 acc = hpc[n * 8];                    // self-loop term
    int m = cnt[n]; if (m > CAP) m = CAP;
    const int m4 = (m + 3) >> 2;
    const int4* ip = (const int4*)(ell + n * CAP);
    int t = 0;
    for (; t + 2 <= m4; t += 2) {               // 8 independent gathers in flight
        const int4 s0 = ip[t], s1 = ip[t + 1];
        const float4 g0 = hpc[s0.x * 8], g1 = hpc[s0.y * 8];
        const float4 g2 = hpc[s0.z * 8], g3 = hpc[s0.w * 8];
        const float4 g4 = hpc[s1.x * 8], g5 = hpc[s1.y * 8];
        const float4 g6 = hpc[s1.z * 8], g7 = hpc[s1.w * 8];
        acc.x += ((g0.x + g1.x) + (g2.x + g3.x)) + ((g4.x + g5.x) + (g6.x + g7.x));
        acc.y += ((g0.y + g1.y) + (g2.y + g3.y)) + ((g4.y + g5.y) + (g6.y + g7.y));
        acc.z += ((g0.z + g1.z) + (g2.z + g3.z)) + ((g4.z + g5.z) + (g6.z + g7.z));
        acc.w += ((g0.w + g1.w) + (g2.w + g3.w)) + ((g4.w + g5.w) + (g6.w + g7.w));
    }
    if (t < m4) {
        const int4 s = ip[t];
        const float4 g0 = hpc[s.x * 8], g1 = hpc[s.y * 8];
        const float4 g2 = hpc[s.z * 8], g3 = hpc[s.w * 8];
        acc.x += (g0.x + g1.x) + (g2.x + g3.x);
        acc.y += (g0.y + g1.y) + (g2.y + g3.y);
        acc.z += (g0.z + g1.z) + (g2.z + g3.z);
        acc.w += (g0.w + g1.w) + (g2.w + g3.w);
    }
    const float d = dis[n];
    float4 r;
    if (MODE == 0) {
        r.x = acc.x * d; r.y = acc.y * d; r.z = acc.z * d; r.w = acc.w * d;
    } else if (MODE == 1) {
        const float d2 = d * d;
        r.x = acc.x * d2; r.y = acc.y * d2; r.z = acc.z * d2; r.w = acc.w * d2;
    } else {
        const float a1 = c1[n], a2 = c2[n];
        const float4 w1 = ((const float4*)v1)[c];
        const float4 w2 = ((const float4*)v2)[c];
        const float4 bb = ((const float4*)b4)[c];
        r.x = fmaf(acc.x, d, fmaf(a1, w1.x, fmaf(a2, w2.x, bb.x)));
        r.y = fmaf(acc.y, d, fmaf(a1, w1.y, fmaf(a2, w2.y, bb.y)));
        r.z = fmaf(acc.z, d, fmaf(a1, w1.z, fmaf(a2, w2.z, bb.z)));
        r.w = fmaf(acc.w, d, fmaf(a1, w1.w, fmaf(a2, w2.w, bb.w)));
    }
    ((float4*)out)[idx] = r;
}

// Register-blocked GEMM (round 6, proven no-spill): thread = (4 cols, node-pair).
// MODE: 2 = relu(acc + b) * dis ; 3 = raw acc
template<int K, int STRIDE, int FOUT, int G, int MODE>
__global__ void gemm_rb_kernel(const float* __restrict__ X, const float* __restrict__ W,
                               const float* __restrict__ bias, const float* __restrict__ dis,
                               float* __restrict__ out) {
    constexpr int CG  = FOUT / 4;
    constexpr int NT  = CG * G;
    constexpr int NPB = 2 * G;
    constexpr int RS  = STRIDE + 4;
    __shared__ float xs[NPB * RS];
    const int tid = threadIdx.x;
    const int n0  = blockIdx.x * NPB;

    constexpr int C4 = STRIDE / 4;
    const float4* Xv = (const float4*)(X + (size_t)n0 * STRIDE);
    for (int i = tid; i < NPB * C4; i += NT) {
        const int nl = i / C4, r = i - nl * C4;
        float4 v = make_float4(0.f, 0.f, 0.f, 0.f);
        if (n0 + nl < NN) v = Xv[nl * C4 + r];
        *(float4*)(xs + nl * RS + r * 4) = v;
    }
    __syncthreads();

    const int cg = tid % CG;
    const int g  = tid / CG;
    const float* x0 = xs + (2 * g) * RS;
    const float* x1 = xs + (2 * g + 1) * RS;
    const float4* Wv = (const float4*)W;

    float4 a0 = make_float4(0.f, 0.f, 0.f, 0.f);
    float4 a1 = make_float4(0.f, 0.f, 0.f, 0.f);
#pragma unroll 8
    for (int k = 0; k < K; ++k) {
        const float4 w = Wv[k * CG + cg];
        const float v0 = x0[k], v1 = x1[k];
        a0.x = fmaf(v0, w.x, a0.x); a0.y = fmaf(v0, w.y, a0.y);
        a0.z = fmaf(v0, w.z, a0.z); a0.w = fmaf(v0, w.w, a0.w);
        a1.x = fmaf(v1, w.x, a1.x); a1.y = fmaf(v1, w.y, a1.y);
        a1.z = fmaf(v1, w.z, a1.z); a1.w = fmaf(v1, w.w, a1.w);
    }

    const int node0 = n0 + 2 * g, node1 = node0 + 1;
    float4 b4 = make_float4(0.f, 0.f, 0.f, 0.f);
    if (MODE == 2) b4 = ((const float4*)bias)[cg];
#pragma unroll
    for (int h = 0; h < 2; ++h) {
        const int node = h ? node1 : node0;
        if (node >= NN) continue;
        float4 a = h ? a1 : a0;
        float4 r;
        if (MODE == 2) {
            const float d = dis[node];
            r.x = fmaxf(a.x + b4.x, 0.f) * d; r.y = fmaxf(a.y + b4.y, 0.f) * d;
            r.z = fmaxf(a.z + b4.z, 0.f) * d; r.w = fmaxf(a.w + b4.w, 0.f) * d;
        } else {
            r = a;
        }
        ((float4*)(out + (size_t)node * FOUT))[cg] = r;
    }
}

extern "C" void kernel_launch(void* const* d_in, const int* in_sizes, int n_in,
                              void* d_out, int out_size, void* d_ws, size_t ws_size,
                              hipStream_t stream) {
    const float* x  = (const float*)d_in[0];
    const int*   ei = (const int*)d_in[1];           // int32 (harness converts)
    const float* W1 = (const float*)d_in[2]; const float* b1 = (const float*)d_in[3];
    const float* W2 = (const float*)d_in[4]; const float* b2 = (const float*)d_in[5];
    const float* W3 = (const float*)d_in[6]; const float* b3 = (const float*)d_in[7];
    const float* W4 = (const float*)d_in[8]; const float* b4 = (const float*)d_in[9];
    float* out = (float*)d_out;

    const int E = in_sizes[1] / 2;          // 800000
    const int* row = ei;
    const int* col = ei + E;

    // Workspace (4B elems, 16B-aligned sections), ~46 MB:
    int*   cnt  = (int*)d_ws;                       // 50048
    float* dis  = (float*)(cnt + 50048);            // 50056 (uses [NN])
    int*   ell  = (int*)(dis + 50056);              // NN*CAP
    float* c1   = (float*)(ell + (size_t)NN * CAP); // 50056
    float* c1d  = c1 + 50056;                       // 50056 (uses [NN])
    float* c2   = c1d + 50056;                      // 50056
    float* W234 = c2 + 50056;                       // 3072
    float* v1   = W234 + 3072;                      // 32
    float* v2   = v1 + 32;                          // 32
    float* Ba   = v2 + 32;                          // (NN+1)*32
    float* Bb   = Ba + 1600064;                     // (NN+1)*32
    float* Bh   = Bb + 1600064;                     // NN*96

    // 1. zero counters
    hipMemsetAsync(cnt, 0, 50048 * sizeof(int), stream);
    // 2. build ELL (4 edges/thread)
    place_ell_kernel<<<(E / 4 + 255) / 256, 256, 0, stream>>>(row, col, cnt, ell, E);
    // 3. dis + pad + xpad + sentinels
    prep_all_kernel<<<(NN * 32 + 64 + 255) / 256, 256, 0, stream>>>(cnt, ell, x, dis, Ba, Bb, c1d);
    // 4. collapsed weights
    wcomb_kernel<<<1, 1024, 0, stream>>>(W2, W3, W4, b2, b3, W234, v1, v2);
    // 5. layer-1 pre-agg (Ba->Bb) + folded c1 = A.1
    agg32_kernel<0><<<AGB + C1B, 256, 0, stream>>>(Ba, cnt, ell, dis,
        nullptr, nullptr, nullptr, nullptr, nullptr, Bb, dis, c1, c1d);
    // 6. gemm 29->96: h1d = relu(Xa@W1+b1)*dis (Bb->Bh)
    gemm_rb_kernel<29, 32, 96, 8, 2><<<(NN + 15) / 16, 192, 0, stream>>>(Bb, W1, b1, dis, Bh);
    // 7. gemm 96->32: g = h1d@W234 raw (Bh->Ba)
    gemm_rb_kernel<96, 96, 32, 32, 3><<<(NN + 63) / 64, 256, 0, stream>>>(Bh, W234, nullptr, nullptr, Ba);
    // 8. hop 1 (Ba->Bb) + folded c2 = A.(c1*dis)
    agg32_kernel<1><<<AGB + C1B, 256, 0, stream>>>(Ba, cnt, ell, dis,
        nullptr, nullptr, nullptr, nullptr, nullptr, Bb, c1d, c2, nullptr);
    // 9. hop 2 (Bb->Ba)
    agg32_kernel<1><<<AGB, 256, 0, stream>>>(Bb, cnt, ell, dis,
        nullptr, nullptr, nullptr, nullptr, nullptr, Ba, nullptr, nullptr, nullptr);
    // 10. hop 3 + rank-1 bias fixups (Ba->out)
    agg32_kernel<2><<<AGB, 256, 0, stream>>>(Ba, cnt, ell, dis,
        c1, c2, v1, v2, b4, out, nullptr, nullptr, nullptr);
}